// Round 1
// baseline (413.589 us; speedup 1.0000x reference)
//
#include <hip/hip_runtime.h>
#include <hip/hip_bf16.h>
#include <stdint.h>

typedef unsigned short ushort_t;
typedef __attribute__((ext_vector_type(8))) short short8;      // 8 bf16 (MFMA A/B frag)
typedef __attribute__((ext_vector_type(8))) ushort_t ushort8;  // staging vector
typedef __attribute__((ext_vector_type(4))) float floatx4;     // MFMA C/D frag

#define MFMA16(a, b, c) __builtin_amdgcn_mfma_f32_16x16x32_bf16(a, b, c, 0, 0, 0)

// ---- problem constants ----
#define BATCH 4
#define SEQ 4096
#define DIM 256
#define HEADS 4
#define DHEAD 64
#define INNER 256
#define MROWS (BATCH * SEQ)   // 16384
#define NQKV (3 * INNER)      // 768

__device__ __forceinline__ ushort_t f2bf(float f) {
    uint32_t u = __builtin_bit_cast(uint32_t, f);
    uint32_t r = (u + 0x7FFFu + ((u >> 16) & 1u)) >> 16;
    return (ushort_t)r;
}
__device__ __forceinline__ float bf2f(ushort_t h) {
    uint32_t u = ((uint32_t)h) << 16;
    return __builtin_bit_cast(float, u);
}

// ---------------- stage 0: fp32 -> bf16 conversion ----------------
// x [16384,256] -> xb ; w_qkv [768,256] -> wqkvb (first 256 rows scaled by 0.125) ;
// w_out [256,256] -> woutb
__global__ __launch_bounds__(256) void convert_kernel(
    const float* __restrict__ x, const float* __restrict__ wqkv,
    const float* __restrict__ wout,
    ushort_t* __restrict__ xb, ushort_t* __restrict__ wqkvb,
    ushort_t* __restrict__ woutb) {
    const int64_t NX = (int64_t)MROWS * DIM;        // 4194304
    const int64_t NW = (int64_t)NQKV * DIM;         // 196608
    const int64_t NO = (int64_t)DIM * INNER;        // 65536
    int64_t idx = (int64_t)blockIdx.x * blockDim.x + threadIdx.x;
    int64_t stride = (int64_t)gridDim.x * blockDim.x;
    for (int64_t i = idx; i < NX + NW + NO; i += stride) {
        if (i < NX) {
            xb[i] = f2bf(x[i]);
        } else if (i < NX + NW) {
            int64_t j = i - NX;
            float s = (j < (int64_t)INNER * DIM) ? 0.125f : 1.0f;  // q rows get softmax scale
            wqkvb[j] = f2bf(wqkv[j] * s);
        } else {
            int64_t j = i - NX - NW;
            woutb[j] = f2bf(wout[j]);
        }
    }
}

// ---------------- stage 1: qkv = x @ w_qkv^T, scatter to per-head layout ----------------
// A [M=16384, K=256] bf16 row-major; B [N=768, K=256] bf16 row-major.
// wave computes 16 rows x 64 cols. q/k/v written as [b,h,n,d] bf16.
__global__ __launch_bounds__(256) void qkv_gemm(
    const ushort_t* __restrict__ A, const ushort_t* __restrict__ B,
    ushort_t* __restrict__ q, ushort_t* __restrict__ k, ushort_t* __restrict__ v) {
    const int K = DIM;
    int wid = threadIdx.x >> 6, lane = threadIdx.x & 63;
    int gw = blockIdx.x * 4 + wid;
    int jt = gw % (NQKV / 64);   // 12 col tiles
    int it = gw / (NQKV / 64);   // 1024 row tiles
    int row = it * 16 + (lane & 15);
    int kc_off = (lane >> 4) * 8;

    floatx4 acc[4] = {};
    for (int kk = 0; kk < K; kk += 32) {
        short8 a = *(const short8*)(A + (int64_t)row * K + kk + kc_off);
#pragma unroll
        for (int t = 0; t < 4; ++t) {
            int col = jt * 64 + t * 16 + (lane & 15);
            short8 b = *(const short8*)(B + (int64_t)col * K + kk + kc_off);
            acc[t] = MFMA16(a, b, acc[t]);
        }
    }
    int r0 = it * 16 + (lane >> 4) * 4;
#pragma unroll
    for (int t = 0; t < 4; ++t) {
        int col = jt * 64 + t * 16 + (lane & 15);
        int part = col >> 8;          // 0=q 1=k 2=v
        int rem = col & 255;
        int h = rem >> 6, d = rem & 63;
        ushort_t* dst = (part == 0) ? q : ((part == 1) ? k : v);
#pragma unroll
        for (int r = 0; r < 4; ++r) {
            int rr = r0 + r;
            int bb = rr >> 12, n = rr & 4095;
            dst[((((int64_t)bb * HEADS + h) * SEQ) + n) * DHEAD + d] = f2bf(acc[t][r]);
        }
    }
}

// ---------------- stage 2: flash attention per (b,h), Q-tile = 64 rows ----------------
// grid = 16 bh * 64 qtiles; 4 waves, each owns 16 q rows.
__global__ __launch_bounds__(256) void attn_kernel(
    const ushort_t* __restrict__ Qg, const ushort_t* __restrict__ Kg,
    const ushort_t* __restrict__ Vg, ushort_t* __restrict__ Og) {
    const int D = DHEAD;
    int bh = blockIdx.x >> 6;   // 0..15
    int qt = blockIdx.x & 63;   // 0..63
    int wid = threadIdx.x >> 6, lane = threadIdx.x & 63;
    int tid = threadIdx.x;

    __shared__ ushort_t Kt[64 * 64];       // [key][d], XOR-swizzled
    __shared__ ushort_t Vt[64 * 64];       // [d][key] (transposed), XOR-swizzled
    __shared__ ushort_t Pt[4][16 * 64];    // per-wave P tile [qrow][key], swizzled

    const ushort_t* qbase = Qg + (int64_t)bh * SEQ * D;
    const ushort_t* kbase = Kg + (int64_t)bh * SEQ * D;
    const ushort_t* vbase = Vg + (int64_t)bh * SEQ * D;

    int kc_off = (lane >> 4) * 8;
    int qrow_frag = qt * 64 + wid * 16 + (lane & 15);
    short8 qf[2];
    qf[0] = *(const short8*)(qbase + (int64_t)qrow_frag * D + 0 + kc_off);
    qf[1] = *(const short8*)(qbase + (int64_t)qrow_frag * D + 32 + kc_off);

    floatx4 accO[4] = {};
    float m_i[4], l_i[4];
#pragma unroll
    for (int r = 0; r < 4; ++r) { m_i[r] = -1e30f; l_i[r] = 0.f; }

    for (int kv = 0; kv < SEQ; kv += 64) {
        __syncthreads();   // protect Kt/Vt from overwrite while others still in PV
        // --- stage K tile (vector copies) ---
#pragma unroll
        for (int i = 0; i < 2; ++i) {
            int c = tid + 256 * i;          // 0..511 chunk id (8 el each)
            int krow = c >> 3, c8 = c & 7;
            ushort8 val = *(const ushort8*)(kbase + (int64_t)(kv + krow) * D + c8 * 8);
            int byte = krow * 128 + c8 * 16;
            byte ^= (krow & 7) << 4;
            *(ushort8*)((char*)Kt + byte) = val;
        }
        // --- stage V transposed ---
#pragma unroll
        for (int i = 0; i < 2; ++i) {
            int c = tid + 256 * i;
            int vrow = c >> 3, c8 = c & 7;  // key=vrow, d = c8*8+j
            ushort8 val = *(const ushort8*)(vbase + (int64_t)(kv + vrow) * D + c8 * 8);
#pragma unroll
            for (int j = 0; j < 8; ++j) {
                int d = c8 * 8 + j;
                int byte = d * 128 + vrow * 2;
                byte ^= (d & 7) << 4;
                *(ushort_t*)((char*)Vt + byte) = val[j];
            }
        }
        __syncthreads();

        // --- S = Q @ K^T  (S[qlocal 0..15][key 0..63]) ---
        floatx4 accS[4] = {};
#pragma unroll
        for (int t = 0; t < 4; ++t) {
#pragma unroll
            for (int kc = 0; kc < 2; ++kc) {
                int krow = t * 16 + (lane & 15);
                int byte = krow * 128 + (kc * 32 + kc_off) * 2;
                byte ^= (krow & 7) << 4;
                short8 bfrag = *(const short8*)((char*)Kt + byte);
                accS[t] = MFMA16(qf[kc], bfrag, accS[t]);
            }
        }

        // --- online softmax: row r of this lane = (lane>>4)*4 + r ---
#pragma unroll
        for (int r = 0; r < 4; ++r) {
            float mx = fmaxf(fmaxf(accS[0][r], accS[1][r]), fmaxf(accS[2][r], accS[3][r]));
#pragma unroll
            for (int s = 1; s < 16; s <<= 1) mx = fmaxf(mx, __shfl_xor(mx, s, 64));
            float mnew = fmaxf(m_i[r], mx);
            float corr = __expf(m_i[r] - mnew);
            m_i[r] = mnew;
            l_i[r] *= corr;
#pragma unroll
            for (int t = 0; t < 4; ++t) accO[t][r] *= corr;
            float rs = 0.f;
#pragma unroll
            for (int t = 0; t < 4; ++t) {
                float p = __expf(accS[t][r] - mnew);
                accS[t][r] = p;
                rs += p;
            }
#pragma unroll
            for (int s = 1; s < 16; s <<= 1) rs += __shfl_xor(rs, s, 64);
            l_i[r] += rs;
        }

        // --- P -> LDS (per-wave region, swizzled) ---
        ushort_t* pw = &Pt[wid][0];
#pragma unroll
        for (int t = 0; t < 4; ++t) {
#pragma unroll
            for (int r = 0; r < 4; ++r) {
                int prow = (lane >> 4) * 4 + r;
                int pcol = t * 16 + (lane & 15);
                int byte = prow * 128 + pcol * 2;
                byte ^= (prow & 7) << 4;
                *(ushort_t*)((char*)pw + byte) = f2bf(accS[t][r]);
            }
        }

        // --- O += P @ V ---
#pragma unroll
        for (int kc = 0; kc < 2; ++kc) {
            int abyte = (lane & 15) * 128 + (kc * 32 + kc_off) * 2;
            abyte ^= ((lane & 15) & 7) << 4;
            short8 pa = *(const short8*)((char*)pw + abyte);
#pragma unroll
            for (int t = 0; t < 4; ++t) {
                int drow = t * 16 + (lane & 15);
                int vbyte = drow * 128 + (kc * 32 + kc_off) * 2;
                vbyte ^= (drow & 7) << 4;
                short8 vb = *(const short8*)((char*)Vt + vbyte);
                accO[t] = MFMA16(pa, vb, accO[t]);
            }
        }
    }

    // --- epilogue: normalize, write O as [b, n, h*64+d] bf16 ---
    int b = bh >> 2, h = bh & 3;
#pragma unroll
    for (int r = 0; r < 4; ++r) {
        int n = qt * 64 + wid * 16 + (lane >> 4) * 4 + r;
        float inv = 1.f / l_i[r];
#pragma unroll
        for (int t = 0; t < 4; ++t) {
            int d = t * 16 + (lane & 15);
            Og[(((int64_t)b * SEQ + n) * INNER) + h * 64 + d] = f2bf(accO[t][r] * inv);
        }
    }
}

// ---------------- stage 3: out = O @ w_out^T + b_out (fp32 out) ----------------
__global__ __launch_bounds__(256) void proj_gemm(
    const ushort_t* __restrict__ A, const ushort_t* __restrict__ B,
    const float* __restrict__ bias, float* __restrict__ out) {
    const int K = INNER, N = DIM;
    int wid = threadIdx.x >> 6, lane = threadIdx.x & 63;
    int gw = blockIdx.x * 4 + wid;
    int jt = gw % (N / 64);   // 4
    int it = gw / (N / 64);   // 1024
    int row = it * 16 + (lane & 15);
    int kc_off = (lane >> 4) * 8;

    floatx4 acc[4] = {};
    for (int kk = 0; kk < K; kk += 32) {
        short8 a = *(const short8*)(A + (int64_t)row * K + kk + kc_off);
#pragma unroll
        for (int t = 0; t < 4; ++t) {
            int col = jt * 64 + t * 16 + (lane & 15);
            short8 b = *(const short8*)(B + (int64_t)col * K + kk + kc_off);
            acc[t] = MFMA16(a, b, acc[t]);
        }
    }
    int r0 = it * 16 + (lane >> 4) * 4;
#pragma unroll
    for (int t = 0; t < 4; ++t) {
        int col = jt * 64 + t * 16 + (lane & 15);
        float bv = bias[col];
#pragma unroll
        for (int r = 0; r < 4; ++r) {
            out[(int64_t)(r0 + r) * N + col] = acc[t][r] + bv;
        }
    }
}

extern "C" void kernel_launch(void* const* d_in, const int* in_sizes, int n_in,
                              void* d_out, int out_size, void* d_ws, size_t ws_size,
                              hipStream_t stream) {
    const float* x = (const float*)d_in[0];
    const float* w_qkv = (const float*)d_in[1];
    const float* w_out = (const float*)d_in[2];
    const float* b_out = (const float*)d_in[3];
    float* out = (float*)d_out;

    // workspace layout (ushort elements)
    ushort_t* ws = (ushort_t*)d_ws;
    const int64_t NX = (int64_t)MROWS * DIM;       // 4194304
    const int64_t NW = (int64_t)NQKV * DIM;        // 196608
    const int64_t NO = (int64_t)DIM * INNER;       // 65536
    const int64_t NH = (int64_t)BATCH * HEADS * SEQ * DHEAD;  // 4194304
    ushort_t* xb = ws;
    ushort_t* wqkvb = xb + NX;
    ushort_t* woutb = wqkvb + NW;
    ushort_t* qb = woutb + NO;
    ushort_t* kb = qb + NH;
    ushort_t* vb = kb + NH;
    ushort_t* ob = vb + NH;
    // total = 21,233,664 ushorts = 42.5 MB

    convert_kernel<<<2048, 256, 0, stream>>>(x, w_qkv, w_out, xb, wqkvb, woutb);
    // qkv: (M/16)*(N/64) waves = 1024*12 = 12288 -> 3072 blocks
    qkv_gemm<<<3072, 256, 0, stream>>>(xb, wqkvb, qb, kb, vb);
    // attention: 16 bh * 64 qtiles
    attn_kernel<<<16 * 64, 256, 0, stream>>>(qb, kb, vb, ob);
    // proj: 1024*4 waves -> 1024 blocks
    proj_gemm<<<1024, 256, 0, stream>>>(ob, woutb, b_out, out);
}

// Round 2
// 233.754 us; speedup vs baseline: 1.7693x; 1.7693x over previous
//
#include <hip/hip_runtime.h>
#include <hip/hip_bf16.h>
#include <stdint.h>

typedef unsigned short ushort_t;
typedef __attribute__((ext_vector_type(8))) short short8;      // 8 bf16 (MFMA A/B frag)
typedef __attribute__((ext_vector_type(8))) ushort_t ushort8;  // staging vector
typedef __attribute__((ext_vector_type(4))) ushort_t ushort4v; // packed bf16 x4 (8B)
typedef __attribute__((ext_vector_type(4))) float floatx4;     // MFMA C/D frag

#define MFMA16(a, b, c) __builtin_amdgcn_mfma_f32_16x16x32_bf16(a, b, c, 0, 0, 0)

// ---- problem constants ----
#define BATCH 4
#define SEQ 4096
#define DIM 256
#define HEADS 4
#define DHEAD 64
#define INNER 256
#define MROWS (BATCH * SEQ)   // 16384
#define NQKV (3 * INNER)      // 768

__device__ __forceinline__ ushort_t f2bf(float f) {
    uint32_t u = __builtin_bit_cast(uint32_t, f);
    uint32_t r = (u + 0x7FFFu + ((u >> 16) & 1u)) >> 16;
    return (ushort_t)r;
}

// ---------------- stage 0: fp32 -> bf16 conversion ----------------
__global__ __launch_bounds__(256) void convert_kernel(
    const float* __restrict__ x, const float* __restrict__ wqkv,
    const float* __restrict__ wout,
    ushort_t* __restrict__ xb, ushort_t* __restrict__ wqkvb,
    ushort_t* __restrict__ woutb) {
    const int64_t NX = (int64_t)MROWS * DIM;        // 4194304
    const int64_t NW = (int64_t)NQKV * DIM;         // 196608
    const int64_t NO = (int64_t)DIM * INNER;        // 65536
    int64_t idx = (int64_t)blockIdx.x * blockDim.x + threadIdx.x;
    int64_t stride = (int64_t)gridDim.x * blockDim.x;
    for (int64_t i = idx; i < NX + NW + NO; i += stride) {
        if (i < NX) {
            xb[i] = f2bf(x[i]);
        } else if (i < NX + NW) {
            int64_t j = i - NX;
            float s = (j < (int64_t)INNER * DIM) ? 0.125f : 1.0f;  // q rows get softmax scale
            wqkvb[j] = f2bf(wqkv[j] * s);
        } else {
            int64_t j = i - NX - NW;
            woutb[j] = f2bf(wout[j]);
        }
    }
}

// ---------------- stage 1: qkv = x @ w_qkv^T ----------------
// q,k written [b,h,n,d]; v written TRANSPOSED [b,h,d,n].
__global__ __launch_bounds__(256) void qkv_gemm(
    const ushort_t* __restrict__ A, const ushort_t* __restrict__ B,
    ushort_t* __restrict__ q, ushort_t* __restrict__ k, ushort_t* __restrict__ v) {
    const int K = DIM;
    int wid = threadIdx.x >> 6, lane = threadIdx.x & 63;
    int gw = blockIdx.x * 4 + wid;
    int jt = gw % (NQKV / 64);   // 12 col tiles
    int it = gw / (NQKV / 64);   // 1024 row tiles
    int row = it * 16 + (lane & 15);
    int kc_off = (lane >> 4) * 8;

    floatx4 acc[4] = {};
    for (int kk = 0; kk < K; kk += 32) {
        short8 a = *(const short8*)(A + (int64_t)row * K + kk + kc_off);
#pragma unroll
        for (int t = 0; t < 4; ++t) {
            int col = jt * 64 + t * 16 + (lane & 15);
            short8 b = *(const short8*)(B + (int64_t)col * K + kk + kc_off);
            acc[t] = MFMA16(a, b, acc[t]);
        }
    }
    int r0 = it * 16 + (lane >> 4) * 4;
#pragma unroll
    for (int t = 0; t < 4; ++t) {
        int col = jt * 64 + t * 16 + (lane & 15);
        int part = col >> 8;          // 0=q 1=k 2=v
        int rem = col & 255;
        int h = rem >> 6, d = rem & 63;
        if (part == 2) {
            // V transposed: [b,h,d,n]; 4 consecutive n -> one 8B store
            ushort4v pk;
#pragma unroll
            for (int r = 0; r < 4; ++r) pk[r] = f2bf(acc[t][r]);
            int bb = r0 >> 12, n = r0 & 4095;
            *(ushort4v*)(v + ((((int64_t)bb * HEADS + h) * DHEAD) + d) * SEQ + n) = pk;
        } else {
            ushort_t* dst = (part == 0) ? q : k;
#pragma unroll
            for (int r = 0; r < 4; ++r) {
                int rr = r0 + r;
                int bb = rr >> 12, n = rr & 4095;
                dst[((((int64_t)bb * HEADS + h) * SEQ) + n) * DHEAD + d] = f2bf(acc[t][r]);
            }
        }
    }
}

// ---------------- stage 2: flash attention ----------------
// grid = 16 bh * 64 qtiles; 4 waves, each owns 16 q rows.
// K [bh][n][d]; V^T [bh][d][n]. Swapped QK^T (S^T layout), per-lane softmax state.
__global__ __launch_bounds__(256) void attn_kernel(
    const ushort_t* __restrict__ Qg, const ushort_t* __restrict__ Kg,
    const ushort_t* __restrict__ Vtg, ushort_t* __restrict__ Og) {
    int bh = blockIdx.x >> 6;   // 0..15
    int qt = blockIdx.x & 63;   // 0..63
    int wid = threadIdx.x >> 6, lane = threadIdx.x & 63;

    __shared__ ushort_t Kt[2][64 * 64];   // [key][d] swizzled, double-buffered
    __shared__ ushort_t Vt[2][64 * 64];   // [d][key] swizzled, double-buffered
    __shared__ ushort_t Pt[4][16 * 64];   // per-wave P tile [q][key] swizzled

    const ushort_t* qbase = Qg + (int64_t)bh * SEQ * DHEAD;
    const ushort_t* kbase = Kg + (int64_t)bh * SEQ * DHEAD;
    const ushort_t* vtbase = Vtg + (int64_t)bh * DHEAD * SEQ;

    const int q15 = lane & 15;
    const int grp = lane >> 4;
    const int kc_off = grp * 8;

    // Q fragment (held in registers for whole kernel)
    int qrow = qt * 64 + wid * 16 + q15;
    short8 qf[2];
    qf[0] = *(const short8*)(qbase + (int64_t)qrow * DHEAD + kc_off);
    qf[1] = *(const short8*)(qbase + (int64_t)qrow * DHEAD + 32 + kc_off);

    // staging geometry: wave stages chunks c = wid*2 + {0,1}; row = c*8 + (lane>>3), c8 = lane&7
    const int st_row0 = wid * 16 + (lane >> 3) * 1 + 0;  // computed per chunk below
    const int st_c8 = lane & 7;

    floatx4 accO[4] = {};
    float m_i = -1e30f, l_i = 0.f;

    short8 krA[2], vrA[2];

#define LOAD_TILE(KV)                                                                  \
    {                                                                                  \
        _Pragma("unroll") for (int ii = 0; ii < 2; ++ii) {                             \
            int c = wid * 2 + ii;                                                      \
            int row = c * 8 + (lane >> 3);                                             \
            krA[ii] = *(const short8*)(kbase + (int64_t)((KV) + row) * DHEAD + st_c8 * 8); \
            vrA[ii] = *(const short8*)(vtbase + (int64_t)row * SEQ + (KV) + st_c8 * 8);   \
        }                                                                              \
    }

#define STORE_TILE(BUF)                                                                \
    {                                                                                  \
        _Pragma("unroll") for (int ii = 0; ii < 2; ++ii) {                             \
            int c = wid * 2 + ii;                                                      \
            int row = c * 8 + (lane >> 3);                                             \
            int byte = row * 128 + st_c8 * 16;                                         \
            byte ^= (row & 7) << 4;                                                    \
            *(short8*)((char*)Kt[BUF] + byte) = krA[ii];                               \
            *(short8*)((char*)Vt[BUF] + byte) = vrA[ii];                               \
        }                                                                              \
    }

    LOAD_TILE(0);
    STORE_TILE(0);
    __syncthreads();

    ushort_t* pw = &Pt[wid][0];

    for (int it = 0; it < SEQ / 64; ++it) {
        int buf = it & 1;
        if (it < SEQ / 64 - 1) LOAD_TILE((it + 1) * 64);

        // --- S^T = K @ Q^T : accS[t] holds S[key=t*16+grp*4+r][q=q15] ---
        floatx4 accS[4] = {};
#pragma unroll
        for (int t = 0; t < 4; ++t) {
#pragma unroll
            for (int kc = 0; kc < 2; ++kc) {
                int krow = t * 16 + q15;
                int byte = krow * 128 + (kc * 32 + kc_off) * 2;
                byte ^= (krow & 7) << 4;
                short8 kf = *(const short8*)((char*)Kt[buf] + byte);
                accS[t] = MFMA16(kf, qf[kc], accS[t]);
            }
        }

        // --- online softmax (per-lane: full row for q = q15) ---
        float mx = accS[0][0];
#pragma unroll
        for (int t = 0; t < 4; ++t)
#pragma unroll
            for (int r = 0; r < 4; ++r) mx = fmaxf(mx, accS[t][r]);
        mx = fmaxf(mx, __shfl_xor(mx, 16, 64));
        mx = fmaxf(mx, __shfl_xor(mx, 32, 64));
        float mnew = fmaxf(m_i, mx);
        float corr = __expf(m_i - mnew);
        float rs = 0.f;
#pragma unroll
        for (int t = 0; t < 4; ++t)
#pragma unroll
            for (int r = 0; r < 4; ++r) {
                float p = __expf(accS[t][r] - mnew);
                accS[t][r] = p;
                rs += p;
            }
        rs += __shfl_xor(rs, 16, 64);
        rs += __shfl_xor(rs, 32, 64);
        l_i = l_i * corr + rs;
        m_i = mnew;

        // rescale accO rows (corr lives at lane with q15 == row)
#pragma unroll
        for (int r = 0; r < 4; ++r) {
            float cr = __shfl(corr, (lane & 48) | (grp * 4 + r), 64);
#pragma unroll
            for (int t = 0; t < 4; ++t) accO[t][r] *= cr;
        }

        // --- P -> LDS (vectorized: 4 consecutive keys per write) ---
#pragma unroll
        for (int t = 0; t < 4; ++t) {
            ushort4v pk;
#pragma unroll
            for (int r = 0; r < 4; ++r) pk[r] = f2bf(accS[t][r]);
            int byte = q15 * 128 + (t * 16 + grp * 4) * 2;
            byte ^= (q15 & 7) << 4;
            *(ushort4v*)((char*)pw + byte) = pk;
        }

        // --- O += P @ V ---
#pragma unroll
        for (int kc = 0; kc < 2; ++kc) {
            int abyte = q15 * 128 + (kc * 32 + kc_off) * 2;
            abyte ^= (q15 & 7) << 4;
            short8 pa = *(const short8*)((char*)pw + abyte);
#pragma unroll
            for (int t = 0; t < 4; ++t) {
                int drow = t * 16 + q15;
                int vbyte = drow * 128 + (kc * 32 + kc_off) * 2;
                vbyte ^= (drow & 7) << 4;
                short8 vb = *(const short8*)((char*)Vt[buf] + vbyte);
                accO[t] = MFMA16(pa, vb, accO[t]);
            }
        }

        if (it < SEQ / 64 - 1) STORE_TILE(buf ^ 1);
        __syncthreads();
    }

    // --- epilogue: normalize, write O as [b, n, h*64+d] bf16 ---
    int b = bh >> 2, h = bh & 3;
#pragma unroll
    for (int r = 0; r < 4; ++r) {
        float li = __shfl(l_i, (lane & 48) | (grp * 4 + r), 64);
        float inv = 1.f / li;
        int n = qt * 64 + wid * 16 + grp * 4 + r;
#pragma unroll
        for (int t = 0; t < 4; ++t) {
            int d = t * 16 + q15;
            Og[(((int64_t)b * SEQ + n) * INNER) + h * 64 + d] = f2bf(accO[t][r] * inv);
        }
    }
#undef LOAD_TILE
#undef STORE_TILE
}

// ---------------- stage 3: out = O @ w_out^T + b_out (fp32 out) ----------------
__global__ __launch_bounds__(256) void proj_gemm(
    const ushort_t* __restrict__ A, const ushort_t* __restrict__ B,
    const float* __restrict__ bias, float* __restrict__ out) {
    const int K = INNER, N = DIM;
    int wid = threadIdx.x >> 6, lane = threadIdx.x & 63;
    int gw = blockIdx.x * 4 + wid;
    int jt = gw % (N / 64);   // 4
    int it = gw / (N / 64);   // 1024
    int row = it * 16 + (lane & 15);
    int kc_off = (lane >> 4) * 8;

    floatx4 acc[4] = {};
    for (int kk = 0; kk < K; kk += 32) {
        short8 a = *(const short8*)(A + (int64_t)row * K + kk + kc_off);
#pragma unroll
        for (int t = 0; t < 4; ++t) {
            int col = jt * 64 + t * 16 + (lane & 15);
            short8 b = *(const short8*)(B + (int64_t)col * K + kk + kc_off);
            acc[t] = MFMA16(a, b, acc[t]);
        }
    }
    int r0 = it * 16 + (lane >> 4) * 4;
#pragma unroll
    for (int t = 0; t < 4; ++t) {
        int col = jt * 64 + t * 16 + (lane & 15);
        float bv = bias[col];
#pragma unroll
        for (int r = 0; r < 4; ++r) {
            out[(int64_t)(r0 + r) * N + col] = acc[t][r] + bv;
        }
    }
}

extern "C" void kernel_launch(void* const* d_in, const int* in_sizes, int n_in,
                              void* d_out, int out_size, void* d_ws, size_t ws_size,
                              hipStream_t stream) {
    const float* x = (const float*)d_in[0];
    const float* w_qkv = (const float*)d_in[1];
    const float* w_out = (const float*)d_in[2];
    const float* b_out = (const float*)d_in[3];
    float* out = (float*)d_out;

    ushort_t* ws = (ushort_t*)d_ws;
    const int64_t NX = (int64_t)MROWS * DIM;       // 4194304
    const int64_t NW = (int64_t)NQKV * DIM;        // 196608
    const int64_t NO = (int64_t)DIM * INNER;       // 65536
    const int64_t NH = (int64_t)BATCH * HEADS * SEQ * DHEAD;  // 4194304
    ushort_t* xb = ws;
    ushort_t* wqkvb = xb + NX;
    ushort_t* woutb = wqkvb + NW;
    ushort_t* qb = woutb + NO;
    ushort_t* kb = qb + NH;
    ushort_t* vb = kb + NH;      // V^T layout [b,h,d,n]
    ushort_t* ob = vb + NH;

    convert_kernel<<<2048, 256, 0, stream>>>(x, w_qkv, w_out, xb, wqkvb, woutb);
    qkv_gemm<<<3072, 256, 0, stream>>>(xb, wqkvb, qb, kb, vb);
    attn_kernel<<<16 * 64, 256, 0, stream>>>(qb, kb, vb, ob);
    proj_gemm<<<1024, 256, 0, stream>>>(ob, woutb, b_out, out);
}

// Round 3
// 190.755 us; speedup vs baseline: 2.1682x; 1.2254x over previous
//
#include <hip/hip_runtime.h>
#include <hip/hip_bf16.h>
#include <stdint.h>

typedef unsigned short ushort_t;
typedef __attribute__((ext_vector_type(8))) short short8;      // 8 bf16 (MFMA A/B frag)
typedef __attribute__((ext_vector_type(8))) ushort_t ushort8;  // staging vector
typedef __attribute__((ext_vector_type(4))) ushort_t ushort4v; // packed bf16 x4 (8B)
typedef __attribute__((ext_vector_type(4))) float floatx4;     // 16x16 MFMA C/D frag
typedef __attribute__((ext_vector_type(16))) float floatx16;   // 32x32 MFMA C/D frag
typedef __attribute__((ext_vector_type(2))) float floatx2;

#define MFMA16(a, b, c) __builtin_amdgcn_mfma_f32_16x16x32_bf16(a, b, c, 0, 0, 0)
#define MFMA32(a, b, c) __builtin_amdgcn_mfma_f32_32x32x16_bf16(a, b, c, 0, 0, 0)

// ---- problem constants ----
#define BATCH 4
#define SEQ 4096
#define DIM 256
#define HEADS 4
#define DHEAD 64
#define INNER 256
#define MROWS (BATCH * SEQ)   // 16384
#define NQKV (3 * INNER)      // 768

__device__ __forceinline__ ushort_t f2bf(float f) {
    uint32_t u = __builtin_bit_cast(uint32_t, f);
    uint32_t r = (u + 0x7FFFu + ((u >> 16) & 1u)) >> 16;
    return (ushort_t)r;
}

__device__ __forceinline__ float exp2_fast(float x) {
#if __has_builtin(__builtin_amdgcn_exp2f)
    return __builtin_amdgcn_exp2f(x);
#else
    return exp2f(x);
#endif
}

__device__ __forceinline__ unsigned cvtpk_bf16(float lo, float hi) {
    unsigned r;
    asm("v_cvt_pk_bf16_f32 %0, %1, %2" : "=v"(r) : "v"(lo), "v"(hi));
    return r;
}

__device__ __forceinline__ void plswap(unsigned& a, unsigned& b) {
#if __has_builtin(__builtin_amdgcn_permlane32_swap)
    auto rr = __builtin_amdgcn_permlane32_swap(a, b, false, false);
    a = (unsigned)rr[0];
    b = (unsigned)rr[1];
#else
    unsigned sa = (unsigned)__shfl_xor((int)a, 32, 64);
    unsigned sb = (unsigned)__shfl_xor((int)b, 32, 64);
    bool upper = (threadIdx.x & 32) != 0;
    unsigned na = upper ? sb : a;
    unsigned nb = upper ? b : sa;
    a = na;
    b = nb;
#endif
}

// ---------------- stage 0: fp32 -> bf16 conversion ----------------
// q rows of w_qkv get softmax scale * log2(e): softmax runs in exp2 space.
__global__ __launch_bounds__(256) void convert_kernel(
    const float* __restrict__ x, const float* __restrict__ wqkv,
    const float* __restrict__ wout,
    ushort_t* __restrict__ xb, ushort_t* __restrict__ wqkvb,
    ushort_t* __restrict__ woutb) {
    const int64_t NX = (int64_t)MROWS * DIM;        // 4194304
    const int64_t NW = (int64_t)NQKV * DIM;         // 196608
    const int64_t NO = (int64_t)DIM * INNER;        // 65536
    const float QS = 0.125f * 1.4426950408889634f;  // scale * log2(e)
    int64_t idx = (int64_t)blockIdx.x * blockDim.x + threadIdx.x;
    int64_t stride = (int64_t)gridDim.x * blockDim.x;
    for (int64_t i = idx; i < NX + NW + NO; i += stride) {
        if (i < NX) {
            xb[i] = f2bf(x[i]);
        } else if (i < NX + NW) {
            int64_t j = i - NX;
            float s = (j < (int64_t)INNER * DIM) ? QS : 1.0f;
            wqkvb[j] = f2bf(wqkv[j] * s);
        } else {
            int64_t j = i - NX - NW;
            woutb[j] = f2bf(wout[j]);
        }
    }
}

// ---------------- stage 1: qkv = x @ w_qkv^T ----------------
// q,k written [b,h,n,d]; v written TRANSPOSED [b,h,d,n].
__global__ __launch_bounds__(256) void qkv_gemm(
    const ushort_t* __restrict__ A, const ushort_t* __restrict__ B,
    ushort_t* __restrict__ q, ushort_t* __restrict__ k, ushort_t* __restrict__ v) {
    const int K = DIM;
    int wid = threadIdx.x >> 6, lane = threadIdx.x & 63;
    int gw = blockIdx.x * 4 + wid;
    int jt = gw % (NQKV / 64);   // 12 col tiles
    int it = gw / (NQKV / 64);   // 1024 row tiles
    int row = it * 16 + (lane & 15);
    int kc_off = (lane >> 4) * 8;

    floatx4 acc[4] = {};
    for (int kk = 0; kk < K; kk += 32) {
        short8 a = *(const short8*)(A + (int64_t)row * K + kk + kc_off);
#pragma unroll
        for (int t = 0; t < 4; ++t) {
            int col = jt * 64 + t * 16 + (lane & 15);
            short8 b = *(const short8*)(B + (int64_t)col * K + kk + kc_off);
            acc[t] = MFMA16(a, b, acc[t]);
        }
    }
    int r0 = it * 16 + (lane >> 4) * 4;
#pragma unroll
    for (int t = 0; t < 4; ++t) {
        int col = jt * 64 + t * 16 + (lane & 15);
        int part = col >> 8;          // 0=q 1=k 2=v
        int rem = col & 255;
        int h = rem >> 6, d = rem & 63;
        if (part == 2) {
            ushort4v pk;
#pragma unroll
            for (int r = 0; r < 4; ++r) pk[r] = f2bf(acc[t][r]);
            int bb = r0 >> 12, n = r0 & 4095;
            *(ushort4v*)(v + ((((int64_t)bb * HEADS + h) * DHEAD) + d) * SEQ + n) = pk;
        } else {
            ushort_t* dst = (part == 0) ? q : k;
#pragma unroll
            for (int r = 0; r < 4; ++r) {
                int rr = r0 + r;
                int bb = rr >> 12, n = rr & 4095;
                dst[((((int64_t)bb * HEADS + h) * SEQ) + n) * DHEAD + d] = f2bf(acc[t][r]);
            }
        }
    }
}

// ---------------- stage 2: flash attention, 32x32 MFMA, in-register softmax ----------------
// grid = 512 (16 bh * 32 q-tiles of 128); 4 waves, each owns 32 q rows.
// Swapped QK^T: accS[kt] C-layout col(lane&31)=q, row=crow(r,hi)=key.
__global__ __launch_bounds__(256) void attn_kernel(
    const ushort_t* __restrict__ Qg, const ushort_t* __restrict__ Kg,
    const ushort_t* __restrict__ Vtg, ushort_t* __restrict__ Og) {
    // XCD-aware swizzle: 512 = 8 XCD * 64 contiguous -> 2 bh per XCD L2
    int bid = blockIdx.x;
    int swz = (bid & 7) * 64 + (bid >> 3);
    int bh = swz >> 5;   // 0..15
    int qt = swz & 31;   // 0..31
    int wid = threadIdx.x >> 6, lane = threadIdx.x & 63;
    const int l31 = lane & 31;
    const int hi = lane >> 5;

    __shared__ ushort_t Kt[2][64 * 64];   // [key][d] swizzled, double-buffered
    __shared__ ushort_t Vt[2][64 * 64];   // [d][key] swizzled, double-buffered

    const ushort_t* qbase = Qg + (int64_t)bh * SEQ * DHEAD;
    const ushort_t* kbase = Kg + (int64_t)bh * SEQ * DHEAD;
    const ushort_t* vtbase = Vtg + (int64_t)bh * DHEAD * SEQ;

    // Q fragments: B-operand, lane holds Q[q0+l31][16s + 8hi + j]
    int q0 = qt * 128 + wid * 32;
    short8 qf[4];
#pragma unroll
    for (int s = 0; s < 4; ++s)
        qf[s] = *(const short8*)(qbase + (int64_t)(q0 + l31) * DHEAD + s * 16 + hi * 8);

    floatx16 accO[2] = {};
    float m_i = 0.f, l_i = 0.f;   // m in exp2-space; 0-init valid with defer-max

    short8 krA[2], vrA[2];
    const int st_c8 = lane & 7;

#define LOAD_TILE(KV)                                                                      \
    {                                                                                      \
        _Pragma("unroll") for (int ii = 0; ii < 2; ++ii) {                                 \
            int c = wid * 2 + ii;                                                          \
            int row = c * 8 + (lane >> 3);                                                 \
            krA[ii] = *(const short8*)(kbase + (int64_t)((KV) + row) * DHEAD + st_c8 * 8); \
            vrA[ii] = *(const short8*)(vtbase + (int64_t)row * SEQ + (KV) + st_c8 * 8);    \
        }                                                                                  \
    }

#define STORE_TILE(BUF)                                                                    \
    {                                                                                      \
        _Pragma("unroll") for (int ii = 0; ii < 2; ++ii) {                                 \
            int c = wid * 2 + ii;                                                          \
            int row = c * 8 + (lane >> 3);                                                 \
            int byte = row * 128 + st_c8 * 16;                                             \
            byte ^= (row & 7) << 4;                                                        \
            *(short8*)((char*)Kt[BUF] + byte) = krA[ii];                                   \
            *(short8*)((char*)Vt[BUF] + byte) = vrA[ii];                                   \
        }                                                                                  \
    }

    LOAD_TILE(0);
    STORE_TILE(0);
    __syncthreads();

    for (int it = 0; it < SEQ / 64; ++it) {
        int buf = it & 1;
        if (it < SEQ / 64 - 1) LOAD_TILE((it + 1) * 64);

        // --- S^T = K @ Q^T, C seeded with -m_i (biased scores) ---
        floatx16 accS[2];
#pragma unroll
        for (int r = 0; r < 16; ++r) { accS[0][r] = -m_i; accS[1][r] = -m_i; }

        __builtin_amdgcn_s_setprio(1);
#pragma unroll
        for (int kt = 0; kt < 2; ++kt) {
#pragma unroll
            for (int s = 0; s < 4; ++s) {
                int key = kt * 32 + l31;
                int byte = key * 128 + s * 32 + hi * 16;
                byte ^= (key & 7) << 4;
                short8 kf = *(const short8*)((char*)Kt[buf] + byte);
                accS[kt] = MFMA32(kf, qf[s], accS[kt]);
            }
        }
        __builtin_amdgcn_s_setprio(0);

        // --- online softmax in exp2 space, defer-max (THR = 8) ---
        float mx = accS[0][0];
#pragma unroll
        for (int kt = 0; kt < 2; ++kt)
#pragma unroll
            for (int r = 0; r < 16; ++r) mx = fmaxf(mx, accS[kt][r]);
        mx = fmaxf(mx, __shfl_xor(mx, 32, 64));

        if (!__all(mx <= 8.f)) {
            float mb = fmaxf(mx, 0.f);
            float corr = exp2_fast(-mb);
            l_i *= corr;
#pragma unroll
            for (int r = 0; r < 16; ++r) {
                int qr = (r & 3) + 8 * (r >> 2) + 4 * hi;
                float cr = __shfl(corr, qr, 64);
                accO[0][r] *= cr;
                accO[1][r] *= cr;
            }
            m_i += mb;
#pragma unroll
            for (int kt = 0; kt < 2; ++kt)
#pragma unroll
                for (int r = 0; r < 16; ++r) accS[kt][r] -= mb;
        }

        floatx2 rs2 = {0.f, 0.f};
#pragma unroll
        for (int kt = 0; kt < 2; ++kt)
#pragma unroll
            for (int r = 0; r < 16; r += 2) {
                float e0 = exp2_fast(accS[kt][r]);
                float e1 = exp2_fast(accS[kt][r + 1]);
                accS[kt][r] = e0;
                accS[kt][r + 1] = e1;
                rs2.x += e0;
                rs2.y += e1;
            }
        float rs = rs2.x + rs2.y;
        rs += __shfl_xor(rs, 32, 64);
        l_i += rs;

        // --- pack P to bf16 and assemble PV A-frags in-register (T12) ---
        short8 pa[4];
#pragma unroll
        for (int kt = 0; kt < 2; ++kt) {
            unsigned w0 = cvtpk_bf16(accS[kt][0], accS[kt][1]);
            unsigned w1 = cvtpk_bf16(accS[kt][2], accS[kt][3]);
            unsigned w2 = cvtpk_bf16(accS[kt][4], accS[kt][5]);
            unsigned w3 = cvtpk_bf16(accS[kt][6], accS[kt][7]);
            unsigned w4 = cvtpk_bf16(accS[kt][8], accS[kt][9]);
            unsigned w5 = cvtpk_bf16(accS[kt][10], accS[kt][11]);
            unsigned w6 = cvtpk_bf16(accS[kt][12], accS[kt][13]);
            unsigned w7 = cvtpk_bf16(accS[kt][14], accS[kt][15]);
            plswap(w0, w2);
            plswap(w1, w3);
            plswap(w4, w6);
            plswap(w5, w7);
            union { unsigned u[4]; short8 s; } f0, f1;
            f0.u[0] = w0; f0.u[1] = w1; f0.u[2] = w2; f0.u[3] = w3;
            f1.u[0] = w4; f1.u[1] = w5; f1.u[2] = w6; f1.u[3] = w7;
            pa[2 * kt] = f0.s;
            pa[2 * kt + 1] = f1.s;
        }

        // --- O += P @ V ---
        __builtin_amdgcn_s_setprio(1);
#pragma unroll
        for (int s = 0; s < 4; ++s) {
#pragma unroll
            for (int o = 0; o < 2; ++o) {
                int vrow = o * 32 + l31;
                int byte = vrow * 128 + s * 32 + hi * 16;
                byte ^= (vrow & 7) << 4;
                short8 vf = *(const short8*)((char*)Vt[buf] + byte);
                accO[o] = MFMA32(pa[s], vf, accO[o]);
            }
        }
        __builtin_amdgcn_s_setprio(0);

        if (it < SEQ / 64 - 1) STORE_TILE(buf ^ 1);
        __syncthreads();
    }

    // --- epilogue: normalize, write O as [b, n, h*64+d] bf16 ---
    int b = bh >> 2, h = bh & 3;
#pragma unroll
    for (int r = 0; r < 16; ++r) {
        int qr = (r & 3) + 8 * (r >> 2) + 4 * hi;
        float li = __shfl(l_i, qr, 64);
        float inv = 1.f / li;
        int n = q0 + qr;
#pragma unroll
        for (int o = 0; o < 2; ++o) {
            int d = o * 32 + l31;
            Og[((int64_t)b * SEQ + n) * INNER + h * 64 + d] = f2bf(accO[o][r] * inv);
        }
    }
#undef LOAD_TILE
#undef STORE_TILE
}

// ---------------- stage 3: out = O @ w_out^T + b_out (fp32 out) ----------------
__global__ __launch_bounds__(256) void proj_gemm(
    const ushort_t* __restrict__ A, const ushort_t* __restrict__ B,
    const float* __restrict__ bias, float* __restrict__ out) {
    const int K = INNER, N = DIM;
    int wid = threadIdx.x >> 6, lane = threadIdx.x & 63;
    int gw = blockIdx.x * 4 + wid;
    int jt = gw % (N / 64);   // 4
    int it = gw / (N / 64);   // 1024
    int row = it * 16 + (lane & 15);
    int kc_off = (lane >> 4) * 8;

    floatx4 acc[4] = {};
    for (int kk = 0; kk < K; kk += 32) {
        short8 a = *(const short8*)(A + (int64_t)row * K + kk + kc_off);
#pragma unroll
        for (int t = 0; t < 4; ++t) {
            int col = jt * 64 + t * 16 + (lane & 15);
            short8 b = *(const short8*)(B + (int64_t)col * K + kk + kc_off);
            acc[t] = MFMA16(a, b, acc[t]);
        }
    }
    int r0 = it * 16 + (lane >> 4) * 4;
#pragma unroll
    for (int t = 0; t < 4; ++t) {
        int col = jt * 64 + t * 16 + (lane & 15);
        float bv = bias[col];
#pragma unroll
        for (int r = 0; r < 4; ++r) {
            out[(int64_t)(r0 + r) * N + col] = acc[t][r] + bv;
        }
    }
}

extern "C" void kernel_launch(void* const* d_in, const int* in_sizes, int n_in,
                              void* d_out, int out_size, void* d_ws, size_t ws_size,
                              hipStream_t stream) {
    const float* x = (const float*)d_in[0];
    const float* w_qkv = (const float*)d_in[1];
    const float* w_out = (const float*)d_in[2];
    const float* b_out = (const float*)d_in[3];
    float* out = (float*)d_out;

    ushort_t* ws = (ushort_t*)d_ws;
    const int64_t NX = (int64_t)MROWS * DIM;       // 4194304
    const int64_t NW = (int64_t)NQKV * DIM;        // 196608
    const int64_t NO = (int64_t)DIM * INNER;       // 65536
    const int64_t NH = (int64_t)BATCH * HEADS * SEQ * DHEAD;  // 4194304
    ushort_t* xb = ws;
    ushort_t* wqkvb = xb + NX;
    ushort_t* woutb = wqkvb + NW;
    ushort_t* qb = woutb + NO;
    ushort_t* kb = qb + NH;
    ushort_t* vb = kb + NH;      // V^T layout [b,h,d,n]
    ushort_t* ob = vb + NH;

    convert_kernel<<<2048, 256, 0, stream>>>(x, w_qkv, w_out, xb, wqkvb, woutb);
    qkv_gemm<<<3072, 256, 0, stream>>>(xb, wqkvb, qb, kb, vb);
    attn_kernel<<<512, 256, 0, stream>>>(qb, kb, vb, ob);
    proj_gemm<<<1024, 256, 0, stream>>>(ob, woutb, b_out, out);
}

// Round 4
// 177.328 us; speedup vs baseline: 2.3323x; 1.0757x over previous
//
#include <hip/hip_runtime.h>
#include <hip/hip_bf16.h>
#include <stdint.h>

typedef unsigned short ushort_t;
typedef __attribute__((ext_vector_type(8))) short short8;      // 8 bf16 (MFMA A/B frag)
typedef __attribute__((ext_vector_type(8))) ushort_t ushort8;  // staging vector
typedef __attribute__((ext_vector_type(4))) ushort_t ushort4v; // packed bf16 x4 (8B)
typedef __attribute__((ext_vector_type(4))) float floatx4;     // 16x16 MFMA C/D frag
typedef __attribute__((ext_vector_type(16))) float floatx16;   // 32x32 MFMA C/D frag

#define MFMA16(a, b, c) __builtin_amdgcn_mfma_f32_16x16x32_bf16(a, b, c, 0, 0, 0)
#define MFMA32(a, b, c) __builtin_amdgcn_mfma_f32_32x32x16_bf16(a, b, c, 0, 0, 0)

// ---- problem constants ----
#define BATCH 4
#define SEQ 4096
#define DIM 256
#define HEADS 4
#define DHEAD 64
#define INNER 256
#define MROWS (BATCH * SEQ)   // 16384
#define NQKV (3 * INNER)      // 768

__device__ __forceinline__ ushort_t f2bf(float f) {
    uint32_t u = __builtin_bit_cast(uint32_t, f);
    uint32_t r = (u + 0x7FFFu + ((u >> 16) & 1u)) >> 16;
    return (ushort_t)r;
}

__device__ __forceinline__ float exp2_fast(float x) {
#if __has_builtin(__builtin_amdgcn_exp2f)
    return __builtin_amdgcn_exp2f(x);
#else
    return exp2f(x);
#endif
}

__device__ __forceinline__ float max3f(float a, float b, float c) {
    return fmaxf(fmaxf(a, b), c);
}

__device__ __forceinline__ unsigned cvtpk_bf16(float lo, float hi) {
    unsigned r;
    asm("v_cvt_pk_bf16_f32 %0, %1, %2" : "=v"(r) : "v"(lo), "v"(hi));
    return r;
}

__device__ __forceinline__ void plswap(unsigned& a, unsigned& b) {
#if __has_builtin(__builtin_amdgcn_permlane32_swap)
    auto rr = __builtin_amdgcn_permlane32_swap(a, b, false, false);
    a = (unsigned)rr[0];
    b = (unsigned)rr[1];
#else
    unsigned sa = (unsigned)__shfl_xor((int)a, 32, 64);
    unsigned sb = (unsigned)__shfl_xor((int)b, 32, 64);
    bool upper = (threadIdx.x & 32) != 0;
    unsigned na = upper ? sb : a;
    unsigned nb = upper ? b : sa;
    a = na;
    b = nb;
#endif
}

// async 16B global -> LDS (wave-uniform LDS base + lane*16 dest; per-lane global src)
__device__ __forceinline__ void gload_lds16(const ushort_t* g, ushort_t* l) {
    __builtin_amdgcn_global_load_lds(
        (__attribute__((address_space(1))) void*)(const_cast<ushort_t*>(g)),
        (__attribute__((address_space(3))) void*)l, 16, 0, 0);
}

// ---------------- stage 0: fp32 -> bf16 conversion ----------------
// q rows of w_qkv get softmax scale * log2(e): softmax runs in exp2 space.
__global__ __launch_bounds__(256) void convert_kernel(
    const float* __restrict__ x, const float* __restrict__ wqkv,
    const float* __restrict__ wout,
    ushort_t* __restrict__ xb, ushort_t* __restrict__ wqkvb,
    ushort_t* __restrict__ woutb) {
    const int64_t NX = (int64_t)MROWS * DIM;        // 4194304
    const int64_t NW = (int64_t)NQKV * DIM;         // 196608
    const int64_t NO = (int64_t)DIM * INNER;        // 65536
    const float QS = 0.125f * 1.4426950408889634f;  // scale * log2(e)
    int64_t idx = (int64_t)blockIdx.x * blockDim.x + threadIdx.x;
    int64_t stride = (int64_t)gridDim.x * blockDim.x;
    for (int64_t i = idx; i < NX + NW + NO; i += stride) {
        if (i < NX) {
            xb[i] = f2bf(x[i]);
        } else if (i < NX + NW) {
            int64_t j = i - NX;
            float s = (j < (int64_t)INNER * DIM) ? QS : 1.0f;
            wqkvb[j] = f2bf(wqkv[j] * s);
        } else {
            int64_t j = i - NX - NW;
            woutb[j] = f2bf(wout[j]);
        }
    }
}

// ---------------- stage 1: qkv = x @ w_qkv^T ----------------
// q,k written [b,h,n,d]; v written TRANSPOSED [b,h,d,n].
__global__ __launch_bounds__(256) void qkv_gemm(
    const ushort_t* __restrict__ A, const ushort_t* __restrict__ B,
    ushort_t* __restrict__ q, ushort_t* __restrict__ k, ushort_t* __restrict__ v) {
    const int K = DIM;
    int wid = threadIdx.x >> 6, lane = threadIdx.x & 63;
    int gw = blockIdx.x * 4 + wid;
    int jt = gw % (NQKV / 64);   // 12 col tiles
    int it = gw / (NQKV / 64);   // 1024 row tiles
    int row = it * 16 + (lane & 15);
    int kc_off = (lane >> 4) * 8;

    floatx4 acc[4] = {};
    for (int kk = 0; kk < K; kk += 32) {
        short8 a = *(const short8*)(A + (int64_t)row * K + kk + kc_off);
#pragma unroll
        for (int t = 0; t < 4; ++t) {
            int col = jt * 64 + t * 16 + (lane & 15);
            short8 b = *(const short8*)(B + (int64_t)col * K + kk + kc_off);
            acc[t] = MFMA16(a, b, acc[t]);
        }
    }
    int r0 = it * 16 + (lane >> 4) * 4;
#pragma unroll
    for (int t = 0; t < 4; ++t) {
        int col = jt * 64 + t * 16 + (lane & 15);
        int part = col >> 8;          // 0=q 1=k 2=v
        int rem = col & 255;
        int h = rem >> 6, d = rem & 63;
        if (part == 2) {
            ushort4v pk;
#pragma unroll
            for (int r = 0; r < 4; ++r) pk[r] = f2bf(acc[t][r]);
            int bb = r0 >> 12, n = r0 & 4095;
            *(ushort4v*)(v + ((((int64_t)bb * HEADS + h) * DHEAD) + d) * SEQ + n) = pk;
        } else {
            ushort_t* dst = (part == 0) ? q : k;
#pragma unroll
            for (int r = 0; r < 4; ++r) {
                int rr = r0 + r;
                int bb = rr >> 12, n = rr & 4095;
                dst[((((int64_t)bb * HEADS + h) * SEQ) + n) * DHEAD + d] = f2bf(acc[t][r]);
            }
        }
    }
}

// ---------------- stage 2: flash attention, KVBLK=128, global_load_lds staging ----------------
// grid = 512 (16 bh * 32 q-tiles of 128); 4 waves, each owns 32 q rows.
// LDS layout (per buf, 32KB): K d-major slots: slot = s*256 + hi*128 + key (16B each),
// stored at linear slot f(slot) = slot ^ ((slot>>7)&7).  V: slot = ks*128 + hik*64 + d.
__global__ __launch_bounds__(256, 2) void attn_kernel(
    const ushort_t* __restrict__ Qg, const ushort_t* __restrict__ Kg,
    const ushort_t* __restrict__ Vtg, ushort_t* __restrict__ Og) {
    int bid = blockIdx.x;
    int swz = (bid & 7) * 64 + (bid >> 3);   // XCD-aware, bijective (512 % 8 == 0)
    int bh = swz >> 5;   // 0..15
    int qt = swz & 31;   // 0..31
    int tid = threadIdx.x;
    int wid = tid >> 6, lane = tid & 63;
    const int l31 = lane & 31;
    const int hi = lane >> 5;

    __shared__ ushort_t SM[2][16384] __attribute__((aligned(16)));  // 64 KB

    const ushort_t* qbase = Qg + (int64_t)bh * SEQ * DHEAD;
    const ushort_t* kbase = Kg + (int64_t)bh * SEQ * DHEAD;
    const ushort_t* vtbase = Vtg + (int64_t)bh * DHEAD * SEQ;

    // Q fragments (B-operand): lane holds Q[q0+l31][s*16 + hi*8 + j]
    int q0 = qt * 128 + wid * 32;
    short8 qf[4];
#pragma unroll
    for (int s = 0; s < 4; ++s)
        qf[s] = *(const short8*)(qbase + (int64_t)(q0 + l31) * DHEAD + s * 16 + hi * 8);

    // ---- staging setup: thread handles linear 16B slots L = jj*256 + tid ----
    const ushort_t* kp[4];
    const ushort_t* vp[4];
    ushort_t* kld[4];
    ushort_t* vld[4];
#pragma unroll
    for (int jj = 0; jj < 4; ++jj) {
        int L = jj * 256 + tid;
        int sl = L ^ ((L >> 7) & 7);   // involution
        int s_ = sl >> 8, hi_ = (sl >> 7) & 1, key_ = sl & 127;
        kp[jj] = kbase + key_ * DHEAD + s_ * 16 + hi_ * 8;
        int ks_ = sl >> 7, hik_ = (sl >> 6) & 1, d_ = sl & 63;
        vp[jj] = vtbase + (int64_t)d_ * SEQ + ks_ * 16 + hik_ * 8;
        kld[jj] = &SM[0][(jj * 256 + wid * 64) * 8];
        vld[jj] = &SM[0][8192 + (jj * 256 + wid * 64) * 8];
    }

#define STAGE(BUF)                                           \
    {                                                        \
        _Pragma("unroll") for (int jj = 0; jj < 4; ++jj) {   \
            gload_lds16(kp[jj], kld[jj] + (BUF) * 16384);    \
            gload_lds16(vp[jj], vld[jj] + (BUF) * 16384);    \
            kp[jj] += 128 * DHEAD;                           \
            vp[jj] += 128;                                   \
        }                                                    \
    }

    // per-lane LDS read bases
    int bS[4];
#pragma unroll
    for (int s = 0; s < 4; ++s) bS[s] = hi * 2048 + ((l31 * 16) ^ ((s * 2 + hi) << 4));
    const int tV = hi * 1024 + l31 * 16;

    floatx16 accO[2] = {};
    floatx16 mseed = {};              // all elements = -m_i
    float m_i = 0.f, l_i = 0.f;       // exp2-space; 0-init valid with defer-max

    STAGE(0);
    __syncthreads();

    for (int it = 0; it < SEQ / 128; ++it) {
        int buf = it & 1;
        const char* smc = (const char*)SM + buf * 32768;
        const char* smv = smc + 16384;
        if (it < SEQ / 128 - 1) STAGE(buf ^ 1);

        // --- S^T = K @ Q^T, C seeded with mseed = -m_i ---
        floatx16 accS[4];
        __builtin_amdgcn_s_setprio(1);
#pragma unroll
        for (int s = 0; s < 4; ++s) {
#pragma unroll
            for (int kt = 0; kt < 4; ++kt) {
                short8 kf = *(const short8*)(smc + bS[s] + s * 4096 + kt * 512);
                accS[kt] = MFMA32(kf, qf[s], s == 0 ? mseed : accS[kt]);
            }
        }
        __builtin_amdgcn_s_setprio(0);

        // --- max over 64 biased scores (4 parallel max3 chains) ---
        float mk[4];
#pragma unroll
        for (int kt = 0; kt < 4; ++kt) {
            float t0 = max3f(accS[kt][0], accS[kt][1], accS[kt][2]);
            t0 = max3f(t0, accS[kt][3], accS[kt][4]);
            t0 = max3f(t0, accS[kt][5], accS[kt][6]);
            t0 = max3f(t0, accS[kt][7], accS[kt][8]);
            t0 = max3f(t0, accS[kt][9], accS[kt][10]);
            t0 = max3f(t0, accS[kt][11], accS[kt][12]);
            t0 = max3f(t0, accS[kt][13], accS[kt][14]);
            mk[kt] = fmaxf(t0, accS[kt][15]);
        }
        float mx = fmaxf(max3f(mk[0], mk[1], mk[2]), mk[3]);
        mx = fmaxf(mx, __shfl_xor(mx, 32, 64));

        // --- defer-max rescale (rare) ---
        if (!__all(mx <= 8.f)) {
            float mb = fmaxf(mx, 0.f);
            float corr = exp2_fast(-mb);
            l_i *= corr;
#pragma unroll
            for (int r = 0; r < 16; ++r) {
                int qr = (r & 3) + 8 * (r >> 2) + 4 * hi;
                float cr = __shfl(corr, qr, 64);
                accO[0][r] *= cr;
                accO[1][r] *= cr;
            }
            m_i += mb;
#pragma unroll
            for (int r = 0; r < 16; ++r) mseed[r] -= mb;
#pragma unroll
            for (int kt = 0; kt < 4; ++kt)
#pragma unroll
                for (int r = 0; r < 16; ++r) accS[kt][r] -= mb;
        }

        // --- exp2 + row-sum (4 parallel chains) ---
        float rs0 = 0.f, rs1 = 0.f, rs2 = 0.f, rs3 = 0.f;
#pragma unroll
        for (int r = 0; r < 16; ++r) {
            float e0 = exp2_fast(accS[0][r]);
            float e1 = exp2_fast(accS[1][r]);
            float e2 = exp2_fast(accS[2][r]);
            float e3 = exp2_fast(accS[3][r]);
            accS[0][r] = e0;
            accS[1][r] = e1;
            accS[2][r] = e2;
            accS[3][r] = e3;
            rs0 += e0;
            rs1 += e1;
            rs2 += e2;
            rs3 += e3;
        }
        float rs = (rs0 + rs1) + (rs2 + rs3);
        rs += __shfl_xor(rs, 32, 64);
        l_i += rs;

        // --- pack P to bf16, assemble PV A-frags in-register (T12) ---
        short8 pa[8];
#pragma unroll
        for (int kt = 0; kt < 4; ++kt) {
            unsigned w0 = cvtpk_bf16(accS[kt][0], accS[kt][1]);
            unsigned w1 = cvtpk_bf16(accS[kt][2], accS[kt][3]);
            unsigned w2 = cvtpk_bf16(accS[kt][4], accS[kt][5]);
            unsigned w3 = cvtpk_bf16(accS[kt][6], accS[kt][7]);
            unsigned w4 = cvtpk_bf16(accS[kt][8], accS[kt][9]);
            unsigned w5 = cvtpk_bf16(accS[kt][10], accS[kt][11]);
            unsigned w6 = cvtpk_bf16(accS[kt][12], accS[kt][13]);
            unsigned w7 = cvtpk_bf16(accS[kt][14], accS[kt][15]);
            plswap(w0, w2);
            plswap(w1, w3);
            plswap(w4, w6);
            plswap(w5, w7);
            union { unsigned u[4]; short8 s; } f0, f1;
            f0.u[0] = w0; f0.u[1] = w1; f0.u[2] = w2; f0.u[3] = w3;
            f1.u[0] = w4; f1.u[1] = w5; f1.u[2] = w6; f1.u[3] = w7;
            pa[2 * kt] = f0.s;
            pa[2 * kt + 1] = f1.s;
        }

        // --- O += P @ V ---
        __builtin_amdgcn_s_setprio(1);
#pragma unroll
        for (int ks = 0; ks < 8; ++ks) {
            int va = tV ^ (ks << 4);
#pragma unroll
            for (int o = 0; o < 2; ++o) {
                short8 vf = *(const short8*)(smv + va + ks * 2048 + o * 512);
                accO[o] = MFMA32(pa[ks], vf, accO[o]);
            }
        }
        __builtin_amdgcn_s_setprio(0);

        __syncthreads();
    }

    // --- epilogue: normalize, write O as [b, n, h*64+d] bf16 ---
    int b = bh >> 2, h = bh & 3;
    float invl = 1.f / l_i;
#pragma unroll
    for (int r = 0; r < 16; ++r) {
        int qr = (r & 3) + 8 * (r >> 2) + 4 * hi;
        float inv = __shfl(invl, qr, 64);
        int n = q0 + qr;
#pragma unroll
        for (int o = 0; o < 2; ++o) {
            int d = o * 32 + l31;
            Og[((int64_t)b * SEQ + n) * INNER + h * 64 + d] = f2bf(accO[o][r] * inv);
        }
    }
#undef STAGE
}

// ---------------- stage 3: out = O @ w_out^T + b_out (fp32 out) ----------------
__global__ __launch_bounds__(256) void proj_gemm(
    const ushort_t* __restrict__ A, const ushort_t* __restrict__ B,
    const float* __restrict__ bias, float* __restrict__ out) {
    const int K = INNER, N = DIM;
    int wid = threadIdx.x >> 6, lane = threadIdx.x & 63;
    int gw = blockIdx.x * 4 + wid;
    int jt = gw % (N / 64);   // 4
    int it = gw / (N / 64);   // 1024
    int row = it * 16 + (lane & 15);
    int kc_off = (lane >> 4) * 8;

    floatx4 acc[4] = {};
    for (int kk = 0; kk < K; kk += 32) {
        short8 a = *(const short8*)(A + (int64_t)row * K + kk + kc_off);
#pragma unroll
        for (int t = 0; t < 4; ++t) {
            int col = jt * 64 + t * 16 + (lane & 15);
            short8 b = *(const short8*)(B + (int64_t)col * K + kk + kc_off);
            acc[t] = MFMA16(a, b, acc[t]);
        }
    }
    int r0 = it * 16 + (lane >> 4) * 4;
#pragma unroll
    for (int t = 0; t < 4; ++t) {
        int col = jt * 64 + t * 16 + (lane & 15);
        float bv = bias[col];
#pragma unroll
        for (int r = 0; r < 4; ++r) {
            out[(int64_t)(r0 + r) * N + col] = acc[t][r] + bv;
        }
    }
}

extern "C" void kernel_launch(void* const* d_in, const int* in_sizes, int n_in,
                              void* d_out, int out_size, void* d_ws, size_t ws_size,
                              hipStream_t stream) {
    const float* x = (const float*)d_in[0];
    const float* w_qkv = (const float*)d_in[1];
    const float* w_out = (const float*)d_in[2];
    const float* b_out = (const float*)d_in[3];
    float* out = (float*)d_out;

    ushort_t* ws = (ushort_t*)d_ws;
    const int64_t NX = (int64_t)MROWS * DIM;       // 4194304
    const int64_t NW = (int64_t)NQKV * DIM;        // 196608
    const int64_t NO = (int64_t)DIM * INNER;       // 65536
    const int64_t NH = (int64_t)BATCH * HEADS * SEQ * DHEAD;  // 4194304
    ushort_t* xb = ws;
    ushort_t* wqkvb = xb + NX;
    ushort_t* woutb = wqkvb + NW;
    ushort_t* qb = woutb + NO;
    ushort_t* kb = qb + NH;
    ushort_t* vb = kb + NH;      // V^T layout [b,h,d,n]
    ushort_t* ob = vb + NH;

    convert_kernel<<<2048, 256, 0, stream>>>(x, w_qkv, w_out, xb, wqkvb, woutb);
    qkv_gemm<<<3072, 256, 0, stream>>>(xb, wqkvb, qb, kb, vb);
    attn_kernel<<<512, 256, 0, stream>>>(qb, kb, vb, ob);
    proj_gemm<<<1024, 256, 0, stream>>>(ob, woutb, b_out, out);
}

// Round 5
// 126.999 us; speedup vs baseline: 3.2566x; 1.3963x over previous
//
#include <hip/hip_runtime.h>
#include <hip/hip_bf16.h>
#include <stdint.h>

typedef unsigned short ushort_t;
typedef __attribute__((ext_vector_type(8))) short short8;      // 8 bf16 (MFMA A/B frag)
typedef __attribute__((ext_vector_type(8))) ushort_t ushort8;  // staging vector
typedef __attribute__((ext_vector_type(4))) ushort_t ushort4v; // packed bf16 x4 (8B)
typedef __attribute__((ext_vector_type(4))) float floatx4;     // 16x16 MFMA C/D frag
typedef __attribute__((ext_vector_type(16))) float floatx16;   // 32x32 MFMA C/D frag

#define MFMA16(a, b, c) __builtin_amdgcn_mfma_f32_16x16x32_bf16(a, b, c, 0, 0, 0)
#define MFMA32(a, b, c) __builtin_amdgcn_mfma_f32_32x32x16_bf16(a, b, c, 0, 0, 0)

// ---- problem constants ----
#define BATCH 4
#define SEQ 4096
#define DIM 256
#define HEADS 4
#define DHEAD 64
#define INNER 256
#define MROWS (BATCH * SEQ)   // 16384
#define NQKV (3 * INNER)      // 768

__device__ __forceinline__ ushort_t f2bf(float f) {
    uint32_t u = __builtin_bit_cast(uint32_t, f);
    uint32_t r = (u + 0x7FFFu + ((u >> 16) & 1u)) >> 16;
    return (ushort_t)r;
}

__device__ __forceinline__ float exp2_fast(float x) {
#if __has_builtin(__builtin_amdgcn_exp2f)
    return __builtin_amdgcn_exp2f(x);
#else
    return exp2f(x);
#endif
}

__device__ __forceinline__ float max3f(float a, float b, float c) {
    return fmaxf(fmaxf(a, b), c);
}

__device__ __forceinline__ unsigned cvtpk_bf16(float lo, float hi) {
    unsigned r;
    asm("v_cvt_pk_bf16_f32 %0, %1, %2" : "=v"(r) : "v"(lo), "v"(hi));
    return r;
}

__device__ __forceinline__ void plswap(unsigned& a, unsigned& b) {
#if __has_builtin(__builtin_amdgcn_permlane32_swap)
    auto rr = __builtin_amdgcn_permlane32_swap(a, b, false, false);
    a = (unsigned)rr[0];
    b = (unsigned)rr[1];
#else
    unsigned sa = (unsigned)__shfl_xor((int)a, 32, 64);
    unsigned sb = (unsigned)__shfl_xor((int)b, 32, 64);
    bool upper = (threadIdx.x & 32) != 0;
    unsigned na = upper ? sb : a;
    unsigned nb = upper ? b : sa;
    a = na;
    b = nb;
#endif
}

// async 16B global -> LDS (wave-uniform LDS base + lane*16 dest; per-lane global src)
__device__ __forceinline__ void gload_lds16(const ushort_t* g, ushort_t* l) {
    __builtin_amdgcn_global_load_lds(
        (__attribute__((address_space(1))) void*)(const_cast<ushort_t*>(g)),
        (__attribute__((address_space(3))) void*)l, 16, 0, 0);
}

// ---------------- stage 0: fp32 -> bf16 conversion ----------------
// q rows of w_qkv get softmax scale * log2(e): softmax runs in exp2 space.
__global__ __launch_bounds__(256) void convert_kernel(
    const float* __restrict__ x, const float* __restrict__ wqkv,
    const float* __restrict__ wout,
    ushort_t* __restrict__ xb, ushort_t* __restrict__ wqkvb,
    ushort_t* __restrict__ woutb) {
    const int64_t NX = (int64_t)MROWS * DIM;        // 4194304
    const int64_t NW = (int64_t)NQKV * DIM;         // 196608
    const int64_t NO = (int64_t)DIM * INNER;        // 65536
    const float QS = 0.125f * 1.4426950408889634f;  // scale * log2(e)
    int64_t idx = (int64_t)blockIdx.x * blockDim.x + threadIdx.x;
    int64_t stride = (int64_t)gridDim.x * blockDim.x;
    for (int64_t i = idx; i < NX + NW + NO; i += stride) {
        if (i < NX) {
            xb[i] = f2bf(x[i]);
        } else if (i < NX + NW) {
            int64_t j = i - NX;
            float s = (j < (int64_t)INNER * DIM) ? QS : 1.0f;
            wqkvb[j] = f2bf(wqkv[j] * s);
        } else {
            int64_t j = i - NX - NW;
            woutb[j] = f2bf(wout[j]);
        }
    }
}

// ---------------- stage 1: qkv = x @ w_qkv^T (block-tiled, LDS-staged B) ----------------
// Block: 128M x 128N, 4 waves (each 32M x 128N). B tile staged once with the
// conflict-free involution f(S)=S^((S>>5)&31) (slot=16B). A strip preloaded to regs.
// q,k written [b,h,n,d]; v written TRANSPOSED [b,h,d,n].
__global__ __launch_bounds__(256) void qkv_gemm(
    const ushort_t* __restrict__ A, const ushort_t* __restrict__ B,
    ushort_t* __restrict__ q, ushort_t* __restrict__ k, ushort_t* __restrict__ v) {
    __shared__ ushort_t Bs[128 * 256] __attribute__((aligned(16)));  // 64 KB
    int bid = blockIdx.x;
    int swz = (bid & 7) * 96 + (bid >> 3);   // 768 = 8 * 96, bijective
    int mt = swz / 6, nb = swz % 6;
    int tid = threadIdx.x;
    int wid = tid >> 6, lane = tid & 63;
    const int l31 = lane & 31, hi = lane >> 5;

    // stage B tile rows [nb*128, nb*128+128) x K=256
    const ushort_t* bsrc = B + (int64_t)nb * 128 * 256;
#pragma unroll
    for (int i = 0; i < 16; ++i) {
        int L = i * 256 + tid;
        int sl = L ^ ((L >> 5) & 31);   // involution (bits0-4 ^= bits5-9)
        gload_lds16(bsrc + (sl >> 5) * 256 + (sl & 31) * 8, &Bs[L * 8]);
    }

    // preload A fragments: 32 rows x K=256 per wave
    int m0 = mt * 128 + wid * 32;
    const ushort_t* abase = A + (int64_t)(m0 + l31) * 256 + hi * 8;
    short8 af[16];
#pragma unroll
    for (int s = 0; s < 16; ++s) af[s] = *(const short8*)(abase + s * 16);

    __syncthreads();

    floatx16 acc[4] = {};
    __builtin_amdgcn_s_setprio(1);
#pragma unroll
    for (int s = 0; s < 16; ++s) {
#pragma unroll
        for (int nt = 0; nt < 4; ++nt) {
            int n = nt * 32 + l31;
            int byte = (n * 512 + s * 32 + hi * 16) ^ ((n & 31) << 4);
            short8 bf = *(const short8*)((const char*)Bs + byte);
            acc[nt] = MFMA32(af[s], bf, acc[nt]);
        }
    }
    __builtin_amdgcn_s_setprio(0);

    int part = nb >> 1;   // 0=q, 1=k, 2=v (each part spans 2 N-blocks of 128)
    if (part < 2) {
        ushort_t* dst = (part == 0) ? q : k;
#pragma unroll
        for (int nt = 0; nt < 4; ++nt) {
            int cc = (nb * 128 + nt * 32 + l31) & 255;
            int h = cc >> 6, d = cc & 63;
#pragma unroll
            for (int r = 0; r < 16; ++r) {
                int m = m0 + (r & 3) + 8 * (r >> 2) + 4 * hi;
                int bb = m >> 12, n = m & 4095;
                dst[((((int64_t)bb * HEADS + h) * SEQ) + n) * DHEAD + d] = f2bf(acc[nt][r]);
            }
        }
    } else {
        // V transposed [b,h,d,n]: regs 4g..4g+3 are 4 consecutive rows -> 8B store
#pragma unroll
        for (int nt = 0; nt < 4; ++nt) {
            int cc = (nb * 128 + nt * 32 + l31) & 255;
            int h = cc >> 6, d = cc & 63;
#pragma unroll
            for (int g = 0; g < 4; ++g) {
                int m = m0 + g * 8 + hi * 4;
                int bb = m >> 12, n = m & 4095;
                ushort4v pk;
#pragma unroll
                for (int r = 0; r < 4; ++r) pk[r] = f2bf(acc[nt][g * 4 + r]);
                *(ushort4v*)(v + ((((int64_t)bb * HEADS + h) * DHEAD) + d) * SEQ + n) = pk;
            }
        }
    }
}

// ---------------- stage 2: flash attention, KVBLK=128, global_load_lds staging ----------------
// grid = 512 (16 bh * 32 q-tiles of 128); 4 waves, each owns 32 q rows.
__global__ __launch_bounds__(256, 2) void attn_kernel(
    const ushort_t* __restrict__ Qg, const ushort_t* __restrict__ Kg,
    const ushort_t* __restrict__ Vtg, ushort_t* __restrict__ Og) {
    int bid = blockIdx.x;
    int swz = (bid & 7) * 64 + (bid >> 3);   // XCD-aware, bijective (512 % 8 == 0)
    int bh = swz >> 5;   // 0..15
    int qt = swz & 31;   // 0..31
    int tid = threadIdx.x;
    int wid = tid >> 6, lane = tid & 63;
    const int l31 = lane & 31;
    const int hi = lane >> 5;

    __shared__ ushort_t SM[2][16384] __attribute__((aligned(16)));  // 64 KB

    const ushort_t* qbase = Qg + (int64_t)bh * SEQ * DHEAD;
    const ushort_t* kbase = Kg + (int64_t)bh * SEQ * DHEAD;
    const ushort_t* vtbase = Vtg + (int64_t)bh * DHEAD * SEQ;

    // Q fragments (B-operand): lane holds Q[q0+l31][s*16 + hi*8 + j]
    int q0 = qt * 128 + wid * 32;
    short8 qf[4];
#pragma unroll
    for (int s = 0; s < 4; ++s)
        qf[s] = *(const short8*)(qbase + (int64_t)(q0 + l31) * DHEAD + s * 16 + hi * 8);

    // ---- staging setup: thread handles linear 16B slots L = jj*256 + tid ----
    const ushort_t* kp[4];
    const ushort_t* vp[4];
    ushort_t* kld[4];
    ushort_t* vld[4];
#pragma unroll
    for (int jj = 0; jj < 4; ++jj) {
        int L = jj * 256 + tid;
        int sl = L ^ ((L >> 7) & 7);   // involution
        int s_ = sl >> 8, hi_ = (sl >> 7) & 1, key_ = sl & 127;
        kp[jj] = kbase + key_ * DHEAD + s_ * 16 + hi_ * 8;
        int ks_ = sl >> 7, hik_ = (sl >> 6) & 1, d_ = sl & 63;
        vp[jj] = vtbase + (int64_t)d_ * SEQ + ks_ * 16 + hik_ * 8;
        kld[jj] = &SM[0][(jj * 256 + wid * 64) * 8];
        vld[jj] = &SM[0][8192 + (jj * 256 + wid * 64) * 8];
    }

#define STAGE(BUF)                                           \
    {                                                        \
        _Pragma("unroll") for (int jj = 0; jj < 4; ++jj) {   \
            gload_lds16(kp[jj], kld[jj] + (BUF) * 16384);    \
            gload_lds16(vp[jj], vld[jj] + (BUF) * 16384);    \
            kp[jj] += 128 * DHEAD;                           \
            vp[jj] += 128;                                   \
        }                                                    \
    }

    // per-lane LDS read bases
    int bS[4];
#pragma unroll
    for (int s = 0; s < 4; ++s) bS[s] = hi * 2048 + ((l31 * 16) ^ ((s * 2 + hi) << 4));
    const int tV = hi * 1024 + l31 * 16;

    floatx16 accO[2] = {};
    floatx16 mseed = {};              // all elements = -m_i
    float m_i = 0.f, l_i = 0.f;       // exp2-space; 0-init valid with defer-max

    STAGE(0);
    __syncthreads();

    for (int it = 0; it < SEQ / 128; ++it) {
        int buf = it & 1;
        const char* smc = (const char*)SM + buf * 32768;
        const char* smv = smc + 16384;
        if (it < SEQ / 128 - 1) STAGE(buf ^ 1);

        // --- S^T = K @ Q^T, C seeded with mseed = -m_i ---
        floatx16 accS[4];
        __builtin_amdgcn_s_setprio(1);
#pragma unroll
        for (int s = 0; s < 4; ++s) {
#pragma unroll
            for (int kt = 0; kt < 4; ++kt) {
                short8 kf = *(const short8*)(smc + bS[s] + s * 4096 + kt * 512);
                accS[kt] = MFMA32(kf, qf[s], s == 0 ? mseed : accS[kt]);
            }
        }
        __builtin_amdgcn_s_setprio(0);

        // --- max over 64 biased scores (4 parallel max3 chains) ---
        float mk[4];
#pragma unroll
        for (int kt = 0; kt < 4; ++kt) {
            float t0 = max3f(accS[kt][0], accS[kt][1], accS[kt][2]);
            t0 = max3f(t0, accS[kt][3], accS[kt][4]);
            t0 = max3f(t0, accS[kt][5], accS[kt][6]);
            t0 = max3f(t0, accS[kt][7], accS[kt][8]);
            t0 = max3f(t0, accS[kt][9], accS[kt][10]);
            t0 = max3f(t0, accS[kt][11], accS[kt][12]);
            t0 = max3f(t0, accS[kt][13], accS[kt][14]);
            mk[kt] = fmaxf(t0, accS[kt][15]);
        }
        float mx = fmaxf(max3f(mk[0], mk[1], mk[2]), mk[3]);
        mx = fmaxf(mx, __shfl_xor(mx, 32, 64));

        // --- defer-max rescale (rare) ---
        if (!__all(mx <= 8.f)) {
            float mb = fmaxf(mx, 0.f);
            float corr = exp2_fast(-mb);
            l_i *= corr;
#pragma unroll
            for (int r = 0; r < 16; ++r) {
                int qr = (r & 3) + 8 * (r >> 2) + 4 * hi;
                float cr = __shfl(corr, qr, 64);
                accO[0][r] *= cr;
                accO[1][r] *= cr;
            }
            m_i += mb;
#pragma unroll
            for (int r = 0; r < 16; ++r) mseed[r] -= mb;
#pragma unroll
            for (int kt = 0; kt < 4; ++kt)
#pragma unroll
                for (int r = 0; r < 16; ++r) accS[kt][r] -= mb;
        }

        // --- exp2 + row-sum (4 parallel chains) ---
        float rs0 = 0.f, rs1 = 0.f, rs2 = 0.f, rs3 = 0.f;
#pragma unroll
        for (int r = 0; r < 16; ++r) {
            float e0 = exp2_fast(accS[0][r]);
            float e1 = exp2_fast(accS[1][r]);
            float e2 = exp2_fast(accS[2][r]);
            float e3 = exp2_fast(accS[3][r]);
            accS[0][r] = e0;
            accS[1][r] = e1;
            accS[2][r] = e2;
            accS[3][r] = e3;
            rs0 += e0;
            rs1 += e1;
            rs2 += e2;
            rs3 += e3;
        }
        float rs = (rs0 + rs1) + (rs2 + rs3);
        rs += __shfl_xor(rs, 32, 64);
        l_i += rs;

        // --- pack P to bf16, assemble PV A-frags in-register (T12) ---
        short8 pa[8];
#pragma unroll
        for (int kt = 0; kt < 4; ++kt) {
            unsigned w0 = cvtpk_bf16(accS[kt][0], accS[kt][1]);
            unsigned w1 = cvtpk_bf16(accS[kt][2], accS[kt][3]);
            unsigned w2 = cvtpk_bf16(accS[kt][4], accS[kt][5]);
            unsigned w3 = cvtpk_bf16(accS[kt][6], accS[kt][7]);
            unsigned w4 = cvtpk_bf16(accS[kt][8], accS[kt][9]);
            unsigned w5 = cvtpk_bf16(accS[kt][10], accS[kt][11]);
            unsigned w6 = cvtpk_bf16(accS[kt][12], accS[kt][13]);
            unsigned w7 = cvtpk_bf16(accS[kt][14], accS[kt][15]);
            plswap(w0, w2);
            plswap(w1, w3);
            plswap(w4, w6);
            plswap(w5, w7);
            union { unsigned u[4]; short8 s; } f0, f1;
            f0.u[0] = w0; f0.u[1] = w1; f0.u[2] = w2; f0.u[3] = w3;
            f1.u[0] = w4; f1.u[1] = w5; f1.u[2] = w6; f1.u[3] = w7;
            pa[2 * kt] = f0.s;
            pa[2 * kt + 1] = f1.s;
        }

        // --- O += P @ V ---
        __builtin_amdgcn_s_setprio(1);
#pragma unroll
        for (int ks = 0; ks < 8; ++ks) {
            int va = tV ^ (ks << 4);
#pragma unroll
            for (int o = 0; o < 2; ++o) {
                short8 vf = *(const short8*)(smv + va + ks * 2048 + o * 512);
                accO[o] = MFMA32(pa[ks], vf, accO[o]);
            }
        }
        __builtin_amdgcn_s_setprio(0);

        __syncthreads();
    }

    // --- epilogue: normalize, write O as [b, n, h*64+d] bf16 ---
    int b = bh >> 2, h = bh & 3;
    float invl = 1.f / l_i;
#pragma unroll
    for (int r = 0; r < 16; ++r) {
        int qr = (r & 3) + 8 * (r >> 2) + 4 * hi;
        float inv = __shfl(invl, qr, 64);
        int n = q0 + qr;
#pragma unroll
        for (int o = 0; o < 2; ++o) {
            int d = o * 32 + l31;
            Og[((int64_t)b * SEQ + n) * INNER + h * 64 + d] = f2bf(accO[o][r] * inv);
        }
    }
#undef STAGE
}

// ---------------- stage 3: out = O @ w_out^T + b_out (block-tiled, LDS-staged B) ----------------
// Block: 64M x 128N, 4 waves (wid&1 -> M half, wid>>1 -> N half of 64).
__global__ __launch_bounds__(256) void proj_gemm(
    const ushort_t* __restrict__ A, const ushort_t* __restrict__ B,
    const float* __restrict__ bias, float* __restrict__ out) {
    __shared__ ushort_t Bs[128 * 256] __attribute__((aligned(16)));  // 64 KB
    int bid = blockIdx.x;
    int swz = (bid & 7) * 64 + (bid >> 3);   // 512 = 8 * 64
    int mt = swz >> 1, nb = swz & 1;
    int tid = threadIdx.x;
    int wid = tid >> 6, lane = tid & 63;
    const int l31 = lane & 31, hi = lane >> 5;

    const ushort_t* bsrc = B + (int64_t)nb * 128 * 256;
#pragma unroll
    for (int i = 0; i < 16; ++i) {
        int L = i * 256 + tid;
        int sl = L ^ ((L >> 5) & 31);
        gload_lds16(bsrc + (sl >> 5) * 256 + (sl & 31) * 8, &Bs[L * 8]);
    }

    int m0 = mt * 64 + (wid & 1) * 32;
    int nside = wid >> 1;
    const ushort_t* abase = A + (int64_t)(m0 + l31) * 256 + hi * 8;
    short8 af[16];
#pragma unroll
    for (int s = 0; s < 16; ++s) af[s] = *(const short8*)(abase + s * 16);

    __syncthreads();

    floatx16 acc[2] = {};
    __builtin_amdgcn_s_setprio(1);
#pragma unroll
    for (int s = 0; s < 16; ++s) {
#pragma unroll
        for (int nt = 0; nt < 2; ++nt) {
            int n = nside * 64 + nt * 32 + l31;
            int byte = (n * 512 + s * 32 + hi * 16) ^ ((n & 31) << 4);
            short8 bf = *(const short8*)((const char*)Bs + byte);
            acc[nt] = MFMA32(af[s], bf, acc[nt]);
        }
    }
    __builtin_amdgcn_s_setprio(0);

#pragma unroll
    for (int nt = 0; nt < 2; ++nt) {
        int col = nb * 128 + nside * 64 + nt * 32 + l31;
        float bv = bias[col];
#pragma unroll
        for (int r = 0; r < 16; ++r) {
            int m = m0 + (r & 3) + 8 * (r >> 2) + 4 * hi;
            out[(int64_t)m * DIM + col] = acc[nt][r] + bv;
        }
    }
}

extern "C" void kernel_launch(void* const* d_in, const int* in_sizes, int n_in,
                              void* d_out, int out_size, void* d_ws, size_t ws_size,
                              hipStream_t stream) {
    const float* x = (const float*)d_in[0];
    const float* w_qkv = (const float*)d_in[1];
    const float* w_out = (const float*)d_in[2];
    const float* b_out = (const float*)d_in[3];
    float* out = (float*)d_out;

    ushort_t* ws = (ushort_t*)d_ws;
    const int64_t NX = (int64_t)MROWS * DIM;       // 4194304
    const int64_t NW = (int64_t)NQKV * DIM;        // 196608
    const int64_t NO = (int64_t)DIM * INNER;       // 65536
    const int64_t NH = (int64_t)BATCH * HEADS * SEQ * DHEAD;  // 4194304
    ushort_t* xb = ws;
    ushort_t* wqkvb = xb + NX;
    ushort_t* woutb = wqkvb + NW;
    ushort_t* qb = woutb + NO;
    ushort_t* kb = qb + NH;
    ushort_t* vb = kb + NH;      // V^T layout [b,h,d,n]
    ushort_t* ob = vb + NH;

    convert_kernel<<<2048, 256, 0, stream>>>(x, w_qkv, w_out, xb, wqkvb, woutb);
    qkv_gemm<<<768, 256, 0, stream>>>(xb, wqkvb, qb, kb, vb);
    attn_kernel<<<512, 256, 0, stream>>>(qb, kb, vb, ob);
    proj_gemm<<<512, 256, 0, stream>>>(ob, woutb, b_out, out);
}